// Round 5
// baseline (19361.293 us; speedup 1.0000x reference)
//
#include <hip/hip_runtime.h>

#define UNITS 65
#define SEQ   8192
#define BATCH 50
#define LAYER 192   // per-layer v buffer: 16 chunks x stride 12 floats

__device__ __forceinline__ float frcp(float x){ return __builtin_amdgcn_rcpf(x); }
__device__ __forceinline__ float fsigmoid(float x){ return frcp(1.0f + __expf(-x)); }
__device__ __forceinline__ float ftanh(float x){
    float e2 = __expf(2.0f * x);
    return 1.0f - 2.0f * frcp(e2 + 1.0f);
}

// DPP helpers (VALU pipe, no LDS traffic)
template<int CTRL>
__device__ __forceinline__ float dppadd(float x){
    int t = __builtin_amdgcn_update_dpp(0, __float_as_int(x), CTRL, 0xF, 0xF, true);
    return x + __int_as_float(t);
}
template<int CTRL>
__device__ __forceinline__ float dppmov(float x){
    int t = __builtin_amdgcn_update_dpp(0, __float_as_int(x), CTRL, 0xF, 0xF, true);
    return __int_as_float(t);
}
// sum over each quad; every lane of the quad gets the full sum
__device__ __forceinline__ float red4_all(float x){
    x = dppadd<0xB1>(x);   // quad_perm [1,0,3,2]
    x = dppadd<0x4E>(x);   // quad_perm [2,3,0,1]
    return x;
}
// 16-lane row sum; row total lands in lane (16*row + 15)
__device__ __forceinline__ float red16_lane15(float x){
    x = dppadd<0x111>(x);  // row_shr:1
    x = dppadd<0x112>(x);  // row_shr:2
    x = dppadd<0x114>(x);  // row_shr:4
    x = dppadd<0x118>(x);  // row_shr:8
    return x;
}
// barrier WITHOUT vmcnt drain (LDS ordering only) — globals here are block-private
__device__ __forceinline__ void bar_lds(){
    asm volatile("s_waitcnt lgkmcnt(0)\n\ts_barrier" ::: "memory");
}
__device__ __forceinline__ float rdlane(float v, int l){
    return __int_as_float(__builtin_amdgcn_readlane(__float_as_int(v), l));
}

// v layout: k in [0,130): k<65 -> in[k], k>=65 -> h[k-65].
// 16 chunks: size 8 for c<15 (k = 8c..8c+7), chunk 15 = 10 (k = 120..129).
// chunk c at stride-12 base (48 B, 16B-aligned). pads zeroed once, never written.
__device__ __forceinline__ int inpos16(int k){
    return (k < 120) ? ((k >> 3) * 12 + (k & 7)) : (180 + (k - 120));
}
// row k of concatenated [W;U] (K=130), column c
__device__ __forceinline__ float wrow(const float* W, const float* U, int k, int c){
    return (k < 65) ? W[k * 260 + c] : U[(k - 65) * 260 + c];
}

// ---------------------------------------------------------------------------
// Layer-pipelined 3-stack LSTM, ONE element per block, 1024 thr = 16 waves =
// 4 waves/SIMD. Each wave owns 4 units (j = wave*4 + ul) for ALL 3 layers;
// lane = ul*16 + k16, 16-way K-split -> only 40 weight floats/lane (+9 u64):
// weights stay REGISTER-RESIDENT under the 128-VGPR cap (round-4's 88-VGPR
// alloc showed the compiler was re-streaming sunk weight loads from L2 every
// step -- the dominant cost). Reductions are DPP-only (no ds_swizzle):
// red4 per quad -> gate-select by k16&3 -> row_shr:4/8 puts gate-g's full sum
// on lane 12+g -> activation split across lanes 12..15 -> writer lane 15
// gathers i,f,g via row_shr dppmovs. ONE barrier per step.
// ---------------------------------------------------------------------------

// Phase B for one layer's regular units. Writer lane (k16==15) commits state
// and performs WRITES (uses hn_; g_ on lane 15 is the o-gate).
#define LAYERB(aI, aF, aG, aO, CST, ...) do {                                  \
    float qI_ = red4_all(aI), qF_ = red4_all(aF);                              \
    float qG_ = red4_all(aG), qO_ = red4_all(aO);                              \
    float z_ = ((gsel == 0) ? qI_ : (gsel == 1) ? qF_ : (gsel == 2) ? qG_ : qO_); \
    z_ = dppadd<0x114>(z_);             /* += lane-4 (cross-quad) */           \
    z_ = dppadd<0x118>(z_);             /* += lane-8 ; lane 12+g = full sum */ \
    z_ += breg;                                                                \
    float sg_ = frcp(1.0f + __expf(-sk * z_));                                 \
    float g_  = fmaf(sk, sg_, dk);      /* lane12:i 13:f 14:g 15:o */          \
    float gi_ = dppmov<0x113>(g_);      /* lane15 <- lane12 (i) */             \
    float gf_ = dppmov<0x112>(g_);      /* lane15 <- lane13 (f) */             \
    float gg_ = dppmov<0x111>(g_);      /* lane15 <- lane14 (g) */             \
    float cn_ = fmaf(gf_, CST, gi_ * gg_);                                     \
    float hn_ = g_ * ftanh(cn_);                                               \
    if (wr) { CST = cn_; __VA_ARGS__; }                                        \
} while (0)

#define STEP(L0, L1, L2, VB, NB) do {                                          \
    const float* __restrict__ vbase = (VB);                                    \
    float*       __restrict__ nbase = (NB);                                    \
    /* x prefetch issued early; consumed next step (>=1 step of slack) */      \
    float xq1 = 0.0f, ex1 = 0.0f;                                              \
    if (L0) {                                                                  \
        const int tl_ = (s + 2 < SEQ) ? (s + 2) : (SEQ - 1);                   \
        if (wr) xq1 = xrow[(size_t)tl_ * UNITS + j];                           \
        if (wave == 1 && lane == 0) ex1 = xrow[(size_t)tl_ * UNITS + 64];      \
    }                                                                          \
    /* phase A: fused LDS-load + 12 interleaved FMA chains, 10-deep */         \
    const float* vp0_ = vbase + k16 * 12;                                      \
    const float* vp1_ = vbase + LAYER + k16 * 12;                              \
    const float* vp2_ = vbase + 2 * LAYER + k16 * 12;                          \
    float aI0=0,aF0=0,aG0=0,aO0=0, aI1=0,aF1=0,aG1=0,aO1=0,                    \
          aI2=0,aF2=0,aG2=0,aO2=0;                                             \
    _Pragma("unroll")                                                          \
    for (int q4_ = 0; q4_ < 2; ++q4_) {                                        \
        float4 f0_, f1_, f2_;                                                  \
        if (L0) f0_ = *(const float4*)(vp0_ + 4 * q4_);                        \
        if (L1) f1_ = *(const float4*)(vp1_ + 4 * q4_);                        \
        if (L2) f2_ = *(const float4*)(vp2_ + 4 * q4_);                        \
        _Pragma("unroll")                                                      \
        for (int r_ = 0; r_ < 4; ++r_) {                                       \
            const int kk = 4 * q4_ + r_;                                       \
            if (L0) { float s0_ = (&f0_.x)[r_];                                \
                aI0=fmaf(s0_,wI[kk],aI0); aF0=fmaf(s0_,wF[kk],aF0);            \
                aG0=fmaf(s0_,wG[kk],aG0); aO0=fmaf(s0_,wO[kk],aO0); }          \
            if (L1) { float s1_ = (&f1_.x)[r_];                                \
                aI1=fmaf(s1_,wI[kk],aI1); aF1=fmaf(s1_,wF[kk],aF1);            \
                aG1=fmaf(s1_,wG[kk],aG1); aO1=fmaf(s1_,wO[kk],aO1); }          \
            if (L2) { float s2_ = (&f2_.x)[r_];                                \
                aI2=fmaf(s2_,wI[kk],aI2); aF2=fmaf(s2_,wF[kk],aF2);            \
                aG2=fmaf(s2_,wG[kk],aG2); aO2=fmaf(s2_,wO[kk],aO2); }          \
        }                                                                      \
    }                                                                          \
    {   /* tail kk = 8,9 (pads zero for k16<15; weights also zeroed) */        \
        float2 t0_, t1_, t2_;                                                  \
        if (L0) t0_ = *(const float2*)(vp0_ + 8);                              \
        if (L1) t1_ = *(const float2*)(vp1_ + 8);                              \
        if (L2) t2_ = *(const float2*)(vp2_ + 8);                              \
        _Pragma("unroll")                                                      \
        for (int r_ = 0; r_ < 2; ++r_) {                                       \
            const int kk = 8 + r_;                                             \
            if (L0) { float s0_ = (&t0_.x)[r_];                                \
                aI0=fmaf(s0_,wI[kk],aI0); aF0=fmaf(s0_,wF[kk],aF0);            \
                aG0=fmaf(s0_,wG[kk],aG0); aO0=fmaf(s0_,wO[kk],aO0); }          \
            if (L1) { float s1_ = (&t1_.x)[r_];                                \
                aI1=fmaf(s1_,wI[kk],aI1); aF1=fmaf(s1_,wF[kk],aF1);            \
                aG1=fmaf(s1_,wG[kk],aG1); aO1=fmaf(s1_,wO[kk],aO1); }          \
            if (L2) { float s2_ = (&t2_.x)[r_];                                \
                aI2=fmaf(s2_,wI[kk],aI2); aF2=fmaf(s2_,wF[kk],aF2);            \
                aG2=fmaf(s2_,wG[kk],aG2); aO2=fmaf(s2_,wO[kk],aO2); }          \
        }                                                                      \
    }                                                                          \
    /* unit-64 (owner waves 1..3 only): 9-MAC dot + in-wave row reduce */      \
    const bool act64_ = (wave == 1) ? (bool)(L0)                               \
                      : (wave == 2) ? (bool)(L1)                               \
                      : (wave == 3) ? (bool)(L2) : false;                      \
    float a64_ = 0.0f;                                                         \
    if (act64_) {                                                              \
        const float* vm_ = vbase + ml * LAYER;                                 \
        float4 uA_ = *(const float4*)(vm_ + p64);                              \
        float4 uB_ = *(const float4*)(vm_ + p64 + 4);                          \
        float  uex_ = (i64 < 2) ? vm_[188 + i64] : 0.0f;                       \
        a64_ = uA_.x * w64[0];                                                 \
        a64_ = fmaf(uA_.y, w64[1], a64_); a64_ = fmaf(uA_.z, w64[2], a64_);    \
        a64_ = fmaf(uA_.w, w64[3], a64_); a64_ = fmaf(uB_.x, w64[4], a64_);    \
        a64_ = fmaf(uB_.y, w64[5], a64_); a64_ = fmaf(uB_.z, w64[6], a64_);    \
        a64_ = fmaf(uB_.w, w64[7], a64_); a64_ = fmaf(uex_, w64x, a64_);       \
        a64_ = red16_lane15(a64_);                                             \
    }                                                                          \
    /* phase B per layer + vn writes */                                        \
    if (L0) LAYERB(aI0, aF0, aG0, aO0, c1,                                     \
                   nbase[ipH] = hn_; nbase[LAYER + ipI] = hn_);                \
    if (L1) LAYERB(aI1, aF1, aG1, aO1, c2,                                     \
                   nbase[LAYER + ipH] = hn_; nbase[2 * LAYER + ipI] = hn_);    \
    if (L2) LAYERB(aI2, aF2, aG2, aO2, c3,                                     \
                   nbase[2 * LAYER + ipH] = hn_;                               \
                   orow[(size_t)(s - 2) * UNITS + j] = hn_);                   \
    if (L0) { if (wr) { nbase[ipI] = xq0; xq0 = xq1; } }                       \
    /* unit-64 phase B: wave-uniform via readlane */                           \
    if (act64_) {                                                              \
        float zi_ = rdlane(a64_, 15) + b64i;                                   \
        float zf_ = rdlane(a64_, 31) + b64f;                                   \
        float zg_ = rdlane(a64_, 47) + b64g;                                   \
        float zo_ = rdlane(a64_, 63) + b64o;                                   \
        float gi4_ = fsigmoid(zi_), gf4_ = fsigmoid(zf_);                      \
        float gg4_ = ftanh(zg_),    go4_ = fsigmoid(zo_);                      \
        float cn64_ = fmaf(gf4_, c64, gi4_ * gg4_);                            \
        float hn64_ = go4_ * ftanh(cn64_);                                     \
        c64 = cn64_;                                                           \
        if (lane == 0) {                                                       \
            nbase[ml * LAYER + 189] = hn64_;                 /* own h-64 */    \
            if (wave <= 2) nbase[(ml + 1) * LAYER + 96] = hn64_; /* next in */ \
            else orow[(size_t)(s - 2) * UNITS + 64] = hn64_;                   \
        }                                                                      \
        if (wave == 1) { if (lane == 0) nbase[96] = ex0; ex0 = ex1; }          \
    }                                                                          \
    bar_lds();                                                                 \
} while (0)

// One block per batch element. 1024 threads = 16 waves = 4 waves/SIMD.
// lane = ul*16 + k16: unit j = wave*4 + ul (0..63), K-chunk k16 (0..15).
__global__ __launch_bounds__(1024, 4)
void lstm3_kernel(const float* __restrict__ x, const float* __restrict__ W,
                  const float* __restrict__ U, const float* __restrict__ b,
                  float* __restrict__ out)
{
    const int e    = blockIdx.x;
    const int tid  = threadIdx.x;
    const int wave = tid >> 6, lane = tid & 63;
    const int k16  = lane & 15, ul = lane >> 4;
    const int j    = wave * 4 + ul;
    const int gsel = k16 & 3;
    const bool wr  = (k16 == 15);

    // [parity][layer][LAYER]: per-layer v = [input(65) | h(65)] in 16-chunk layout
    __shared__ __attribute__((aligned(16))) float vbuf[2][3][LAYER];

    // ---- per-thread weights (K-chunk x 4 gates); invalid tail slots = 0 ----
    float wI[10], wF[10], wG[10], wO[10];
    #pragma unroll
    for (int kk = 0; kk < 10; ++kk) {
        const int  k   = 8 * k16 + kk;                // <= 129 always
        const bool val = (kk < 8) || (k16 == 15);
        wI[kk] = val ? wrow(W, U, k, j)       : 0.0f;
        wF[kk] = val ? wrow(W, U, k, 65  + j) : 0.0f;
        wG[kk] = val ? wrow(W, U, k, 130 + j) : 0.0f;
        wO[kk] = val ? wrow(W, U, k, 195 + j) : 0.0f;
    }
    const float breg = b[gsel * 65 + j];
    const float sk   = (gsel == 2) ? 2.0f : 1.0f;  // g-gate: tanh(z)=2*sig(2z)-1
    const float dk   = 1.0f - sk;

    // unit-64 in-wave split: gate g64 = lane>>4, K-slice i64 = lane&15 (8 k + rem)
    const int i64 = lane & 15, g64 = lane >> 4;
    const int p64 = i64 * 12;                      // inpos16(8*i64), contiguous 8
    float w64[8], w64x;
    {
        const int c64c = g64 * 65 + 64;
        #pragma unroll
        for (int r = 0; r < 8; ++r) w64[r] = wrow(W, U, 8 * i64 + r, c64c);
        w64x = (i64 < 2) ? wrow(W, U, 128 + i64, c64c) : 0.0f;
    }
    const float b64i = b[64], b64f = b[129], b64g = b[194], b64o = b[259];
    const int ml = (wave >= 1 && wave <= 3) ? (wave - 1) : 0;

    float c1 = 0, c2 = 0, c3 = 0, c64 = 0;         // cell states

    const float* xrow = x   + (size_t)e * SEQ * UNITS;
    float*       orow = out + (size_t)e * SEQ * UNITS;
    const int ipI = inpos16(j), ipH = inpos16(65 + j);

    // ---- init: zero LDS (pads + h-parts must be 0), then v0.in = x(0) ----
    for (int i = tid; i < 2 * 3 * LAYER; i += 1024) ((float*)&vbuf[0][0][0])[i] = 0.0f;
    __syncthreads();
    if (wr)  vbuf[0][0][ipI] = xrow[j];
    if (wave == 1 && lane == 0) vbuf[0][0][96] = xrow[64];   // inpos16(64)=96
    __syncthreads();

    // x prefetch: xq0 holds x(s+1) value at end of step s
    float xq0 = 0, ex0 = 0;
    if (wr) xq0 = xrow[UNITS + j];
    if (wave == 1 && lane == 0) ex0 = xrow[UNITS + 64];

    float* const vb0 = &vbuf[0][0][0];
    float* const vb1 = &vbuf[1][0][0];
    int s = 0;
    STEP(1, 0, 0, vb0, vb1); ++s;               // s=0: layer0 only
    STEP(1, 1, 0, vb1, vb0); ++s;               // s=1: layers 0,1
    for (; s < SEQ - 1; ) {                     // s=2..SEQ-1 (8190 steps, even)
        STEP(1, 1, 1, vb0, vb1); ++s;
        STEP(1, 1, 1, vb1, vb0); ++s;
    }
    STEP(0, 1, 1, vb0, vb1); ++s;               // s=SEQ: layers 1,2
    STEP(0, 0, 1, vb1, vb0);                    // s=SEQ+1: layer 2 drains
}

// Dense head, in place on d_out: out_row = row @ Wd + bd. One thread per row.
__global__ __launch_bounds__(256)
void dense_kernel(float* __restrict__ io,
                  const float* __restrict__ Wd,
                  const float* __restrict__ bd)
{
    __shared__ __attribute__((aligned(16))) float wS[65 * 68];
    __shared__ float bS[65];
    for (int i = threadIdx.x; i < 65 * 65; i += 256) {
        int r = i / 65, c = i - r * 65;
        wS[r * 68 + c] = Wd[i];
    }
    if (threadIdx.x < 65) bS[threadIdx.x] = bd[threadIdx.x];
    __syncthreads();

    const size_t row  = (size_t)blockIdx.x * 256 + threadIdx.x;
    const size_t base = row * 65;

    float r[65];
    #pragma unroll
    for (int k = 0; k < 65; ++k) r[k] = io[base + k];

    for (int ct = 0; ct < 16; ++ct) {
        const int c = ct * 4;
        float a0 = bS[c], a1 = bS[c + 1], a2 = bS[c + 2], a3 = bS[c + 3];
        #pragma unroll
        for (int k = 0; k < 65; ++k) {
            const float4 wv = *reinterpret_cast<const float4*>(&wS[k * 68 + c]);
            a0 += r[k] * wv.x;
            a1 += r[k] * wv.y;
            a2 += r[k] * wv.z;
            a3 += r[k] * wv.w;
        }
        io[base + c]     = a0;
        io[base + c + 1] = a1;
        io[base + c + 2] = a2;
        io[base + c + 3] = a3;
    }
    float a = bS[64];
    #pragma unroll
    for (int k = 0; k < 65; ++k) a += r[k] * wS[k * 68 + 64];
    io[base + 64] = a;
}

extern "C" void kernel_launch(void* const* d_in, const int* in_sizes, int n_in,
                              void* d_out, int out_size, void* d_ws, size_t ws_size,
                              hipStream_t stream)
{
    const float* x  = (const float*)d_in[0];
    const float* W  = (const float*)d_in[1];
    const float* U  = (const float*)d_in[2];
    const float* b  = (const float*)d_in[3];
    const float* Wd = (const float*)d_in[4];
    const float* bd = (const float*)d_in[5];
    float* out = (float*)d_out;

    hipLaunchKernelGGL(lstm3_kernel, dim3(BATCH), dim3(1024), 0, stream, x, W, U, b, out);
    hipLaunchKernelGGL(dense_kernel, dim3(1600), dim3(256), 0, stream, out, Wd, bd);
}

// Round 6
// 15171.156 us; speedup vs baseline: 1.2762x; 1.2762x over previous
//
#include <hip/hip_runtime.h>

#define UNITS 65
#define SEQ   8192
#define BATCH 50
#define LAYER 192   // per-layer v buffer: 16 chunks x stride 12 floats

typedef float v2f __attribute__((ext_vector_type(2)));

__device__ __forceinline__ float frcp(float x){ return __builtin_amdgcn_rcpf(x); }
__device__ __forceinline__ float fsigmoid(float x){ return frcp(1.0f + __expf(-x)); }
__device__ __forceinline__ float ftanh(float x){
    float e2 = __expf(2.0f * x);
    return 1.0f - 2.0f * frcp(e2 + 1.0f);
}

// DPP helpers (VALU pipe, no LDS traffic)
template<int CTRL>
__device__ __forceinline__ float dppadd(float x){
    int t = __builtin_amdgcn_update_dpp(0, __float_as_int(x), CTRL, 0xF, 0xF, true);
    return x + __int_as_float(t);
}
template<int CTRL>
__device__ __forceinline__ float dppmov(float x){
    int t = __builtin_amdgcn_update_dpp(0, __float_as_int(x), CTRL, 0xF, 0xF, true);
    return __int_as_float(t);
}
// sum over each quad; every lane of the quad gets the full sum
__device__ __forceinline__ float red4_all(float x){
    x = dppadd<0xB1>(x);   // quad_perm [1,0,3,2]
    x = dppadd<0x4E>(x);   // quad_perm [2,3,0,1]
    return x;
}
// 16-lane row sum; row total lands in lane (16*row + 15)
__device__ __forceinline__ float red16_lane15(float x){
    x = dppadd<0x111>(x);  // row_shr:1
    x = dppadd<0x112>(x);  // row_shr:2
    x = dppadd<0x114>(x);  // row_shr:4
    x = dppadd<0x118>(x);  // row_shr:8
    return x;
}
// barrier WITHOUT vmcnt drain (LDS ordering only) — globals here are block-private
__device__ __forceinline__ void bar_lds(){
    asm volatile("s_waitcnt lgkmcnt(0)\n\ts_barrier" ::: "memory");
}
__device__ __forceinline__ float rdlane(float v, int l){
    return __int_as_float(__builtin_amdgcn_readlane(__float_as_int(v), l));
}

// v layout: k in [0,130): k<65 -> in[k], k>=65 -> h[k-65].
// 16 chunks: size 8 for c<15 (k = 8c..8c+7), chunk 15 = 10 (k = 120..129).
// chunk c at stride-12 base (48 B, 16B-aligned). pads zeroed once, never written.
__device__ __forceinline__ int inpos16(int k){
    return (k < 120) ? ((k >> 3) * 12 + (k & 7)) : (180 + (k - 120));
}
// row k of concatenated [W;U] (K=130), column c
__device__ __forceinline__ float wrow(const float* W, const float* U, int k, int c){
    return (k < 65) ? W[k * 260 + c] : U[(k - 65) * 260 + c];
}

// ---------------------------------------------------------------------------
// Layer-pipelined 3-stack LSTM, ONE element per block, 1024 thr = 16 waves =
// 4 waves/SIMD. Each wave owns 4 units (j = wave*4 + ul) for ALL 3 layers;
// lane = ul*16 + k16, 16-way K-split.
// ROUND-6 changes (schedule identical to round 5):
//  (1) weights PINNED in VGPRs via opaque asm ("+v") after load — round-5's
//      VGPR_Count=60 proved the compiler sank the 49 weight floats into the
//      t-loop and re-streamed them from L2 every step (~200KB/step/CU, the
//      dominant invariant ~1500cy/step stall across rounds 1/4/5).
//  (2) packed fp32 FMA: gates paired (I,F),(G,O) as float2, v_pk_fma_f32
//      via __builtin_elementwise_fma — halves FMA issue (120 -> 60/lane).
// Reductions DPP-only; ONE barrier per step.
// ---------------------------------------------------------------------------

// Phase B for one layer's regular units. Writer lane (k16==15) commits state
// and performs WRITES (uses hn_; g_ on lane 15 is the o-gate).
#define LAYERB(aI, aF, aG, aO, CST, ...) do {                                  \
    float qI_ = red4_all(aI), qF_ = red4_all(aF);                              \
    float qG_ = red4_all(aG), qO_ = red4_all(aO);                              \
    float z_ = ((gsel == 0) ? qI_ : (gsel == 1) ? qF_ : (gsel == 2) ? qG_ : qO_); \
    z_ = dppadd<0x114>(z_);             /* += lane-4 (cross-quad) */           \
    z_ = dppadd<0x118>(z_);             /* += lane-8 ; lane 12+g = full sum */ \
    z_ += breg;                                                                \
    float sg_ = frcp(1.0f + __expf(-sk * z_));                                 \
    float g_  = fmaf(sk, sg_, dk);      /* lane12:i 13:f 14:g 15:o */          \
    float gi_ = dppmov<0x113>(g_);      /* lane15 <- lane12 (i) */             \
    float gf_ = dppmov<0x112>(g_);      /* lane15 <- lane13 (f) */             \
    float gg_ = dppmov<0x111>(g_);      /* lane15 <- lane14 (g) */             \
    float cn_ = fmaf(gf_, CST, gi_ * gg_);                                     \
    float hn_ = g_ * ftanh(cn_);                                               \
    if (wr) { CST = cn_; __VA_ARGS__; }                                        \
} while (0)

#define STEP(L0, L1, L2, VB, NB) do {                                          \
    const float* __restrict__ vbase = (VB);                                    \
    float*       __restrict__ nbase = (NB);                                    \
    /* x prefetch issued early; consumed next step (>=1 step of slack) */      \
    float xq1 = 0.0f, ex1 = 0.0f;                                              \
    if (L0) {                                                                  \
        const int tl_ = (s + 2 < SEQ) ? (s + 2) : (SEQ - 1);                   \
        if (wr) xq1 = xrow[(size_t)tl_ * UNITS + j];                           \
        if (wave == 1 && lane == 0) ex1 = xrow[(size_t)tl_ * UNITS + 64];      \
    }                                                                          \
    /* phase A: fused LDS-load + 6 packed FMA chains (3 layers x 2 pairs) */   \
    const float* vp0_ = vbase + k16 * 12;                                      \
    const float* vp1_ = vbase + LAYER + k16 * 12;                              \
    const float* vp2_ = vbase + 2 * LAYER + k16 * 12;                          \
    v2f aIF0={0,0},aGO0={0,0}, aIF1={0,0},aGO1={0,0}, aIF2={0,0},aGO2={0,0};   \
    _Pragma("unroll")                                                          \
    for (int q4_ = 0; q4_ < 2; ++q4_) {                                        \
        float4 f0_, f1_, f2_;                                                  \
        if (L0) f0_ = *(const float4*)(vp0_ + 4 * q4_);                        \
        if (L1) f1_ = *(const float4*)(vp1_ + 4 * q4_);                        \
        if (L2) f2_ = *(const float4*)(vp2_ + 4 * q4_);                        \
        _Pragma("unroll")                                                      \
        for (int r_ = 0; r_ < 4; ++r_) {                                       \
            const int kk = 4 * q4_ + r_;                                       \
            if (L0) { float s0_ = (&f0_.x)[r_]; v2f ss_ = {s0_, s0_};          \
                aIF0 = __builtin_elementwise_fma(ss_, wIF[kk], aIF0);          \
                aGO0 = __builtin_elementwise_fma(ss_, wGO[kk], aGO0); }        \
            if (L1) { float s1_ = (&f1_.x)[r_]; v2f ss_ = {s1_, s1_};          \
                aIF1 = __builtin_elementwise_fma(ss_, wIF[kk], aIF1);          \
                aGO1 = __builtin_elementwise_fma(ss_, wGO[kk], aGO1); }        \
            if (L2) { float s2_ = (&f2_.x)[r_]; v2f ss_ = {s2_, s2_};          \
                aIF2 = __builtin_elementwise_fma(ss_, wIF[kk], aIF2);          \
                aGO2 = __builtin_elementwise_fma(ss_, wGO[kk], aGO2); }        \
        }                                                                      \
    }                                                                          \
    {   /* tail kk = 8,9 (pads zero for k16<15; weights also zeroed) */        \
        float2 t0_, t1_, t2_;                                                  \
        if (L0) t0_ = *(const float2*)(vp0_ + 8);                              \
        if (L1) t1_ = *(const float2*)(vp1_ + 8);                              \
        if (L2) t2_ = *(const float2*)(vp2_ + 8);                              \
        _Pragma("unroll")                                                      \
        for (int r_ = 0; r_ < 2; ++r_) {                                       \
            const int kk = 8 + r_;                                             \
            if (L0) { float s0_ = (&t0_.x)[r_]; v2f ss_ = {s0_, s0_};          \
                aIF0 = __builtin_elementwise_fma(ss_, wIF[kk], aIF0);          \
                aGO0 = __builtin_elementwise_fma(ss_, wGO[kk], aGO0); }        \
            if (L1) { float s1_ = (&t1_.x)[r_]; v2f ss_ = {s1_, s1_};          \
                aIF1 = __builtin_elementwise_fma(ss_, wIF[kk], aIF1);          \
                aGO1 = __builtin_elementwise_fma(ss_, wGO[kk], aGO1); }        \
            if (L2) { float s2_ = (&t2_.x)[r_]; v2f ss_ = {s2_, s2_};          \
                aIF2 = __builtin_elementwise_fma(ss_, wIF[kk], aIF2);          \
                aGO2 = __builtin_elementwise_fma(ss_, wGO[kk], aGO2); }        \
        }                                                                      \
    }                                                                          \
    /* unit-64 (owner waves 1..3 only): 9-MAC dot + in-wave row reduce */      \
    const bool act64_ = (wave == 1) ? (bool)(L0)                               \
                      : (wave == 2) ? (bool)(L1)                               \
                      : (wave == 3) ? (bool)(L2) : false;                      \
    float a64_ = 0.0f;                                                         \
    if (act64_) {                                                              \
        const float* vm_ = vbase + ml * LAYER;                                 \
        float4 uA_ = *(const float4*)(vm_ + p64);                              \
        float4 uB_ = *(const float4*)(vm_ + p64 + 4);                          \
        float  uex_ = (i64 < 2) ? vm_[188 + i64] : 0.0f;                       \
        a64_ = uA_.x * w64[0];                                                 \
        a64_ = fmaf(uA_.y, w64[1], a64_); a64_ = fmaf(uA_.z, w64[2], a64_);    \
        a64_ = fmaf(uA_.w, w64[3], a64_); a64_ = fmaf(uB_.x, w64[4], a64_);    \
        a64_ = fmaf(uB_.y, w64[5], a64_); a64_ = fmaf(uB_.z, w64[6], a64_);    \
        a64_ = fmaf(uB_.w, w64[7], a64_); a64_ = fmaf(uex_, w64x, a64_);       \
        a64_ = red16_lane15(a64_);                                             \
    }                                                                          \
    /* phase B per layer + vn writes */                                        \
    if (L0) LAYERB(aIF0.x, aIF0.y, aGO0.x, aGO0.y, c1,                         \
                   nbase[ipH] = hn_; nbase[LAYER + ipI] = hn_);                \
    if (L1) LAYERB(aIF1.x, aIF1.y, aGO1.x, aGO1.y, c2,                         \
                   nbase[LAYER + ipH] = hn_; nbase[2 * LAYER + ipI] = hn_);    \
    if (L2) LAYERB(aIF2.x, aIF2.y, aGO2.x, aGO2.y, c3,                         \
                   nbase[2 * LAYER + ipH] = hn_;                               \
                   orow[(size_t)(s - 2) * UNITS + j] = hn_);                   \
    if (L0) { if (wr) { nbase[ipI] = xq0; xq0 = xq1; } }                       \
    /* unit-64 phase B: wave-uniform via readlane */                           \
    if (act64_) {                                                              \
        float zi_ = rdlane(a64_, 15) + b64i;                                   \
        float zf_ = rdlane(a64_, 31) + b64f;                                   \
        float zg_ = rdlane(a64_, 47) + b64g;                                   \
        float zo_ = rdlane(a64_, 63) + b64o;                                   \
        float gi4_ = fsigmoid(zi_), gf4_ = fsigmoid(zf_);                      \
        float gg4_ = ftanh(zg_),    go4_ = fsigmoid(zo_);                      \
        float cn64_ = fmaf(gf4_, c64, gi4_ * gg4_);                            \
        float hn64_ = go4_ * ftanh(cn64_);                                     \
        c64 = cn64_;                                                           \
        if (lane == 0) {                                                       \
            nbase[ml * LAYER + 189] = hn64_;                 /* own h-64 */    \
            if (wave <= 2) nbase[(ml + 1) * LAYER + 96] = hn64_; /* next in */ \
            else orow[(size_t)(s - 2) * UNITS + 64] = hn64_;                   \
        }                                                                      \
        if (wave == 1) { if (lane == 0) nbase[96] = ex0; ex0 = ex1; }          \
    }                                                                          \
    bar_lds();                                                                 \
} while (0)

// One block per batch element. 1024 threads = 16 waves = 4 waves/SIMD.
// lane = ul*16 + k16: unit j = wave*4 + ul (0..63), K-chunk k16 (0..15).
__global__ __launch_bounds__(1024, 4)
void lstm3_kernel(const float* __restrict__ x, const float* __restrict__ W,
                  const float* __restrict__ U, const float* __restrict__ b,
                  float* __restrict__ out)
{
    const int e    = blockIdx.x;
    const int tid  = threadIdx.x;
    const int wave = tid >> 6, lane = tid & 63;
    const int k16  = lane & 15, ul = lane >> 4;
    const int j    = wave * 4 + ul;
    const int gsel = k16 & 3;
    const bool wr  = (k16 == 15);

    // [parity][layer][LAYER]: per-layer v = [input(65) | h(65)] in 16-chunk layout
    __shared__ __attribute__((aligned(16))) float vbuf[2][3][LAYER];

    // ---- per-thread weights, gate-packed (I,F),(G,O); tail slots = 0 ----
    v2f wIF[10], wGO[10];
    #pragma unroll
    for (int kk = 0; kk < 10; ++kk) {
        const int  k   = 8 * k16 + kk;                // <= 129 always
        const bool val = (kk < 8) || (k16 == 15);
        wIF[kk].x = val ? wrow(W, U, k, j)       : 0.0f;
        wIF[kk].y = val ? wrow(W, U, k, 65  + j) : 0.0f;
        wGO[kk].x = val ? wrow(W, U, k, 130 + j) : 0.0f;
        wGO[kk].y = val ? wrow(W, U, k, 195 + j) : 0.0f;
    }
    const float breg = b[gsel * 65 + j];
    const float sk   = (gsel == 2) ? 2.0f : 1.0f;  // g-gate: tanh(z)=2*sig(2z)-1
    const float dk   = 1.0f - sk;

    // unit-64 in-wave split: gate g64 = lane>>4, K-slice i64 = lane&15 (8 k + rem)
    const int i64 = lane & 15, g64 = lane >> 4;
    const int p64 = i64 * 12;                      // inpos16(8*i64), contiguous 8
    float w64[8], w64x;
    {
        const int c64c = g64 * 65 + 64;
        #pragma unroll
        for (int r = 0; r < 8; ++r) w64[r] = wrow(W, U, 8 * i64 + r, c64c);
        w64x = (i64 < 2) ? wrow(W, U, 128 + i64, c64c) : 0.0f;
    }

    // ---- PIN all per-lane weights in VGPRs: the opaque asm becomes the
    // defining instruction of each live value, so the compiler cannot sink
    // or rematerialize the loads inside the t-loop (round-5 failure mode).
    #pragma unroll
    for (int kk = 0; kk < 10; ++kk) {
        asm volatile("" : "+v"(wIF[kk]), "+v"(wGO[kk]));
    }
    #pragma unroll
    for (int r = 0; r < 8; ++r) { asm volatile("" : "+v"(w64[r])); }
    asm volatile("" : "+v"(w64x));

    const float b64i = b[64], b64f = b[129], b64g = b[194], b64o = b[259];
    const int ml = (wave >= 1 && wave <= 3) ? (wave - 1) : 0;

    float c1 = 0, c2 = 0, c3 = 0, c64 = 0;         // cell states

    const float* xrow = x   + (size_t)e * SEQ * UNITS;
    float*       orow = out + (size_t)e * SEQ * UNITS;
    const int ipI = inpos16(j), ipH = inpos16(65 + j);

    // ---- init: zero LDS (pads + h-parts must be 0), then v0.in = x(0) ----
    for (int i = tid; i < 2 * 3 * LAYER; i += 1024) ((float*)&vbuf[0][0][0])[i] = 0.0f;
    __syncthreads();
    if (wr)  vbuf[0][0][ipI] = xrow[j];
    if (wave == 1 && lane == 0) vbuf[0][0][96] = xrow[64];   // inpos16(64)=96
    __syncthreads();

    // x prefetch: xq0 holds x(s+1) value at end of step s
    float xq0 = 0, ex0 = 0;
    if (wr) xq0 = xrow[UNITS + j];
    if (wave == 1 && lane == 0) ex0 = xrow[UNITS + 64];

    float* const vb0 = &vbuf[0][0][0];
    float* const vb1 = &vbuf[1][0][0];
    int s = 0;
    STEP(1, 0, 0, vb0, vb1); ++s;               // s=0: layer0 only
    STEP(1, 1, 0, vb1, vb0); ++s;               // s=1: layers 0,1
    for (; s < SEQ - 1; ) {                     // s=2..SEQ-1 (8190 steps, even)
        STEP(1, 1, 1, vb0, vb1); ++s;
        STEP(1, 1, 1, vb1, vb0); ++s;
    }
    STEP(0, 1, 1, vb0, vb1); ++s;               // s=SEQ: layers 1,2
    STEP(0, 0, 1, vb1, vb0);                    // s=SEQ+1: layer 2 drains
}

// Dense head, in place on d_out: out_row = row @ Wd + bd. One thread per row.
__global__ __launch_bounds__(256)
void dense_kernel(float* __restrict__ io,
                  const float* __restrict__ Wd,
                  const float* __restrict__ bd)
{
    __shared__ __attribute__((aligned(16))) float wS[65 * 68];
    __shared__ float bS[65];
    for (int i = threadIdx.x; i < 65 * 65; i += 256) {
        int r = i / 65, c = i - r * 65;
        wS[r * 68 + c] = Wd[i];
    }
    if (threadIdx.x < 65) bS[threadIdx.x] = bd[threadIdx.x];
    __syncthreads();

    const size_t row  = (size_t)blockIdx.x * 256 + threadIdx.x;
    const size_t base = row * 65;

    float r[65];
    #pragma unroll
    for (int k = 0; k < 65; ++k) r[k] = io[base + k];

    for (int ct = 0; ct < 16; ++ct) {
        const int c = ct * 4;
        float a0 = bS[c], a1 = bS[c + 1], a2 = bS[c + 2], a3 = bS[c + 3];
        #pragma unroll
        for (int k = 0; k < 65; ++k) {
            const float4 wv = *reinterpret_cast<const float4*>(&wS[k * 68 + c]);
            a0 += r[k] * wv.x;
            a1 += r[k] * wv.y;
            a2 += r[k] * wv.z;
            a3 += r[k] * wv.w;
        }
        io[base + c]     = a0;
        io[base + c + 1] = a1;
        io[base + c + 2] = a2;
        io[base + c + 3] = a3;
    }
    float a = bS[64];
    #pragma unroll
    for (int k = 0; k < 65; ++k) a += r[k] * wS[k * 68 + 64];
    io[base + 64] = a;
}

extern "C" void kernel_launch(void* const* d_in, const int* in_sizes, int n_in,
                              void* d_out, int out_size, void* d_ws, size_t ws_size,
                              hipStream_t stream)
{
    const float* x  = (const float*)d_in[0];
    const float* W  = (const float*)d_in[1];
    const float* U  = (const float*)d_in[2];
    const float* b  = (const float*)d_in[3];
    const float* Wd = (const float*)d_in[4];
    const float* bd = (const float*)d_in[5];
    float* out = (float*)d_out;

    hipLaunchKernelGGL(lstm3_kernel, dim3(BATCH), dim3(1024), 0, stream, x, W, U, b, out);
    hipLaunchKernelGGL(dense_kernel, dim3(1600), dim3(256), 0, stream, out, Wd, bd);
}

// Round 10
// 15061.938 us; speedup vs baseline: 1.2854x; 1.0073x over previous
//
#include <hip/hip_runtime.h>

#define UNITS 65
#define SEQ   8192
#define BATCH 50
#define LAYER 192   // per-layer v buffer: 16 chunks x stride 12 floats

typedef float v2f __attribute__((ext_vector_type(2)));

__device__ __forceinline__ float frcp(float x){ return __builtin_amdgcn_rcpf(x); }
__device__ __forceinline__ float fsigmoid(float x){ return frcp(1.0f + __expf(-x)); }
__device__ __forceinline__ float ftanh(float x){
    float e2 = __expf(2.0f * x);
    return 1.0f - 2.0f * frcp(e2 + 1.0f);
}

// DPP helpers (VALU pipe, no LDS traffic)
template<int CTRL>
__device__ __forceinline__ float dppadd(float x){
    int t = __builtin_amdgcn_update_dpp(0, __float_as_int(x), CTRL, 0xF, 0xF, true);
    return x + __int_as_float(t);
}
template<int CTRL>
__device__ __forceinline__ float dppmov(float x){
    int t = __builtin_amdgcn_update_dpp(0, __float_as_int(x), CTRL, 0xF, 0xF, true);
    return __int_as_float(t);
}
// sum over each quad; every lane of the quad gets the full sum
__device__ __forceinline__ float red4_all(float x){
    x = dppadd<0xB1>(x);   // quad_perm [1,0,3,2]
    x = dppadd<0x4E>(x);   // quad_perm [2,3,0,1]
    return x;
}
// 16-lane row sum; row total lands in lane (16*row + 15)
__device__ __forceinline__ float red16_lane15(float x){
    x = dppadd<0x111>(x);  // row_shr:1
    x = dppadd<0x112>(x);  // row_shr:2
    x = dppadd<0x114>(x);  // row_shr:4
    x = dppadd<0x118>(x);  // row_shr:8
    return x;
}
// barrier WITHOUT vmcnt drain (LDS ordering only) — globals here are block-private
__device__ __forceinline__ void bar_lds(){
    asm volatile("s_waitcnt lgkmcnt(0)\n\ts_barrier" ::: "memory");
}
__device__ __forceinline__ float rdlane(float v, int l){
    return __int_as_float(__builtin_amdgcn_readlane(__float_as_int(v), l));
}

// v layout: k in [0,130): k<65 -> in[k], k>=65 -> h[k-65].
// 16 chunks: size 8 for c<15 (k = 8c..8c+7), chunk 15 = 10 (k = 120..129).
// chunk c at stride-12 base (48 B, 16B-aligned). pads zeroed once, never written.
__device__ __forceinline__ int inpos16(int k){
    return (k < 120) ? ((k >> 3) * 12 + (k & 7)) : (180 + (k - 120));
}
// row k of concatenated [W;U] (K=130), column c
__device__ __forceinline__ float wrow(const float* W, const float* U, int k, int c){
    return (k < 65) ? W[k * 260 + c] : U[(k - 65) * 260 + c];
}

// ---------------------------------------------------------------------------
// ROUND-10 (= round-8/9 resubmission; GPU never acquired either round).
// Pipeline macro is PIPE3 (round-7's SEQ-collision compile bug fixed).
// Same geometry as rounds 5/6 (16 waves = 4/SIMD, 16-way K-split, packed
// FMA), but the STEP is restructured for LDS<->VALU phase overlap.
// Evidence: rounds 1/4/5/6 all land at ~4400cy/t with ~130-150 ds_read ops/t
// (the one conserved quantity); VALU inst count changes (r6 packed FMA,
// VALUBusy 17.6->13.9) moved time 0% -> step time = serial [LDS drain ~1700cy]
// -> [VALU burst ~1200cy] -> [barrier], because all 16 waves issue all reads
// in lockstep then all wait. Fix:
//  (1) layer-sequential JIT reads, software-pipelined: RD(next layer) issues
//      under PB(current layer)'s DPP/exp chains;
//  (2) wave-rotated layer order (wave%3): ~1/3 of waves read while 2/3
//      compute -> LDS pipe continuously fed. Safe: all reads from vbase, all
//      writes to nbase, no intra-step dependencies.
//  (3) unit-64 LDS loads hoisted to step start (latency hidden under SEQ).
// Weight-pin removed (r6: null). ONE barrier per step.
// ---------------------------------------------------------------------------

// Phase B for one layer's regular units. Writer lane (k16==15) commits state
// and performs WRITES (uses hn_; g_ on lane 15 is the o-gate).
#define LAYERB(aI, aF, aG, aO, CST, ...) do {                                  \
    float qI_ = red4_all(aI), qF_ = red4_all(aF);                              \
    float qG_ = red4_all(aG), qO_ = red4_all(aO);                              \
    float z_ = ((gsel == 0) ? qI_ : (gsel == 1) ? qF_ : (gsel == 2) ? qG_ : qO_); \
    z_ = dppadd<0x114>(z_);             /* += lane-4 (cross-quad) */           \
    z_ = dppadd<0x118>(z_);             /* += lane-8 ; lane 12+g = full sum */ \
    z_ += breg;                                                                \
    float sg_ = frcp(1.0f + __expf(-sk * z_));                                 \
    float g_  = fmaf(sk, sg_, dk);      /* lane12:i 13:f 14:g 15:o */          \
    float gi_ = dppmov<0x113>(g_);      /* lane15 <- lane12 (i) */             \
    float gf_ = dppmov<0x112>(g_);      /* lane15 <- lane13 (f) */             \
    float gg_ = dppmov<0x111>(g_);      /* lane15 <- lane14 (g) */             \
    float cn_ = fmaf(gf_, CST, gi_ * gg_);                                     \
    float hn_ = g_ * ftanh(cn_);                                               \
    if (wr) { CST = cn_; __VA_ARGS__; }                                        \
} while (0)

// per-layer write sets (used as LAYERB tail args)
#define WRT_0  nbase[ipH] = hn_; nbase[LAYER + ipI] = hn_
#define WRT_1  nbase[LAYER + ipH] = hn_; nbase[2 * LAYER + ipI] = hn_
#define WRT_2  nbase[2 * LAYER + ipH] = hn_; orow[(size_t)(s - 2) * UNITS + j] = hn_

// JIT LDS read for layer l (3 ops: 2x b128 + 1x b64)
#define RD(l, Lact) do { if (Lact) {                                           \
    const float* vp_ = vbase + (l) * LAYER + k16 * 12;                         \
    fA##l = *(const float4*)(vp_);                                             \
    fB##l = *(const float4*)(vp_ + 4);                                         \
    fT##l = *(const float2*)(vp_ + 8);                                         \
} } while (0)

// packed FMA chain for layer l (10 k-values -> 20 v_pk_fma_f32)
#define FM(l, Lact) do { if (Lact) {                                           \
    _Pragma("unroll")                                                          \
    for (int r_ = 0; r_ < 4; ++r_) {                                           \
        float s_ = (&fA##l.x)[r_]; v2f ss_ = {s_, s_};                         \
        aIF##l = __builtin_elementwise_fma(ss_, wIF[r_], aIF##l);              \
        aGO##l = __builtin_elementwise_fma(ss_, wGO[r_], aGO##l);              \
    }                                                                          \
    _Pragma("unroll")                                                          \
    for (int r_ = 0; r_ < 4; ++r_) {                                           \
        float s_ = (&fB##l.x)[r_]; v2f ss_ = {s_, s_};                         \
        aIF##l = __builtin_elementwise_fma(ss_, wIF[4 + r_], aIF##l);          \
        aGO##l = __builtin_elementwise_fma(ss_, wGO[4 + r_], aGO##l);          \
    }                                                                          \
    _Pragma("unroll")                                                          \
    for (int r_ = 0; r_ < 2; ++r_) {                                           \
        float s_ = (&fT##l.x)[r_]; v2f ss_ = {s_, s_};                         \
        aIF##l = __builtin_elementwise_fma(ss_, wIF[8 + r_], aIF##l);          \
        aGO##l = __builtin_elementwise_fma(ss_, wGO[8 + r_], aGO##l);          \
    }                                                                          \
} } while (0)

// phase B dispatch for layer l
#define PB0(Lact) do { if (Lact) LAYERB(aIF0.x, aIF0.y, aGO0.x, aGO0.y, c_0, WRT_0); } while (0)
#define PB1(Lact) do { if (Lact) LAYERB(aIF1.x, aIF1.y, aGO1.x, aGO1.y, c_1, WRT_1); } while (0)
#define PB2(Lact) do { if (Lact) LAYERB(aIF2.x, aIF2.y, aGO2.x, aGO2.y, c_2, WRT_2); } while (0)

// software-pipelined 3-layer sequence in order (a,b,c):
// RD(b) issues under PB(a)'s DPP/exp chains, RD(c) under PB(b)'s.
#define PIPE3(a, b, c, La, Lb, Lc) do {                                        \
    RD(a, La); FM(a, La);                                                      \
    RD(b, Lb);                                                                 \
    PB##a(La);                                                                 \
    FM(b, Lb);                                                                 \
    RD(c, Lc);                                                                 \
    PB##b(Lb);                                                                 \
    FM(c, Lc);                                                                 \
    PB##c(Lc);                                                                 \
} while (0)

#define STEP(L0, L1, L2, VB, NB) do {                                          \
    const float* __restrict__ vbase = (VB);                                    \
    float*       __restrict__ nbase = (NB);                                    \
    /* x prefetch issued early; consumed next step (>=1 step of slack) */      \
    float xq1 = 0.0f, ex1 = 0.0f;                                              \
    if (L0) {                                                                  \
        const int tl_ = (s + 2 < SEQ) ? (s + 2) : (SEQ - 1);                   \
        if (wr) xq1 = xrow[(size_t)tl_ * UNITS + j];                           \
        if (wave == 1 && lane == 0) ex1 = xrow[(size_t)tl_ * UNITS + 64];      \
    }                                                                          \
    /* unit-64 LDS loads hoisted: latency hidden under the layer pipeline */   \
    const bool act64_ = (wave == 1) ? (bool)(L0)                               \
                      : (wave == 2) ? (bool)(L1)                               \
                      : (wave == 3) ? (bool)(L2) : false;                      \
    float4 uA_ = {0,0,0,0}, uB_ = {0,0,0,0}; float uex_ = 0.0f;                \
    if (act64_) {                                                              \
        const float* vm_ = vbase + ml * LAYER;                                 \
        uA_ = *(const float4*)(vm_ + p64);                                     \
        uB_ = *(const float4*)(vm_ + p64 + 4);                                 \
        uex_ = (i64 < 2) ? vm_[188 + i64] : 0.0f;                              \
    }                                                                          \
    float4 fA0, fB0, fA1, fB1, fA2, fB2; float2 fT0, fT1, fT2;                 \
    v2f aIF0={0,0},aGO0={0,0}, aIF1={0,0},aGO1={0,0}, aIF2={0,0},aGO2={0,0};   \
    /* wave-rotated layer order: ~1/3 of waves read while 2/3 compute */       \
    if (wro == 0)      PIPE3(0, 1, 2, L0, L1, L2);                             \
    else if (wro == 1) PIPE3(1, 2, 0, L1, L2, L0);                             \
    else               PIPE3(2, 0, 1, L2, L0, L1);                             \
    if (L0) { if (wr) { nbase[ipI] = xq0; xq0 = xq1; } }                       \
    /* unit-64: dot + in-wave row reduce + wave-uniform phase B */             \
    if (act64_) {                                                              \
        float a64_ = uA_.x * w64[0];                                           \
        a64_ = fmaf(uA_.y, w64[1], a64_); a64_ = fmaf(uA_.z, w64[2], a64_);    \
        a64_ = fmaf(uA_.w, w64[3], a64_); a64_ = fmaf(uB_.x, w64[4], a64_);    \
        a64_ = fmaf(uB_.y, w64[5], a64_); a64_ = fmaf(uB_.z, w64[6], a64_);    \
        a64_ = fmaf(uB_.w, w64[7], a64_); a64_ = fmaf(uex_, w64x, a64_);       \
        a64_ = red16_lane15(a64_);                                             \
        float zi_ = rdlane(a64_, 15) + b64i;                                   \
        float zf_ = rdlane(a64_, 31) + b64f;                                   \
        float zg_ = rdlane(a64_, 47) + b64g;                                   \
        float zo_ = rdlane(a64_, 63) + b64o;                                   \
        float gi4_ = fsigmoid(zi_), gf4_ = fsigmoid(zf_);                      \
        float gg4_ = ftanh(zg_),    go4_ = fsigmoid(zo_);                      \
        float cn64_ = fmaf(gf4_, c64, gi4_ * gg4_);                            \
        float hn64_ = go4_ * ftanh(cn64_);                                     \
        c64 = cn64_;                                                           \
        if (lane == 0) {                                                       \
            nbase[ml * LAYER + 189] = hn64_;                 /* own h-64 */    \
            if (wave <= 2) nbase[(ml + 1) * LAYER + 96] = hn64_; /* next in */ \
            else orow[(size_t)(s - 2) * UNITS + 64] = hn64_;                   \
        }                                                                      \
        if (wave == 1) { if (lane == 0) nbase[96] = ex0; ex0 = ex1; }          \
    }                                                                          \
    bar_lds();                                                                 \
} while (0)

// One block per batch element. 1024 threads = 16 waves = 4 waves/SIMD.
// lane = ul*16 + k16: unit j = wave*4 + ul (0..63), K-chunk k16 (0..15).
__global__ __launch_bounds__(1024, 4)
void lstm3_kernel(const float* __restrict__ x, const float* __restrict__ W,
                  const float* __restrict__ U, const float* __restrict__ b,
                  float* __restrict__ out)
{
    const int e    = blockIdx.x;
    const int tid  = threadIdx.x;
    const int wave = tid >> 6, lane = tid & 63;
    const int k16  = lane & 15, ul = lane >> 4;
    const int j    = wave * 4 + ul;
    const int gsel = k16 & 3;
    const bool wr  = (k16 == 15);
    const int wro  = wave % 3;         // rotated layer start

    // [parity][layer][LAYER]: per-layer v = [input(65) | h(65)] in 16-chunk layout
    __shared__ __attribute__((aligned(16))) float vbuf[2][3][LAYER];

    // ---- per-thread weights, gate-packed (I,F),(G,O); tail slots = 0 ----
    v2f wIF[10], wGO[10];
    #pragma unroll
    for (int kk = 0; kk < 10; ++kk) {
        const int  k   = 8 * k16 + kk;                // <= 129 always
        const bool val = (kk < 8) || (k16 == 15);
        wIF[kk].x = val ? wrow(W, U, k, j)       : 0.0f;
        wIF[kk].y = val ? wrow(W, U, k, 65  + j) : 0.0f;
        wGO[kk].x = val ? wrow(W, U, k, 130 + j) : 0.0f;
        wGO[kk].y = val ? wrow(W, U, k, 195 + j) : 0.0f;
    }
    const float breg = b[gsel * 65 + j];
    const float sk   = (gsel == 2) ? 2.0f : 1.0f;  // g-gate: tanh(z)=2*sig(2z)-1
    const float dk   = 1.0f - sk;

    // unit-64 in-wave split: gate g64 = lane>>4, K-slice i64 = lane&15 (8 k + rem)
    const int i64 = lane & 15, g64 = lane >> 4;
    const int p64 = i64 * 12;                      // inpos16(8*i64), contiguous 8
    float w64[8], w64x;
    {
        const int c64c = g64 * 65 + 64;
        #pragma unroll
        for (int r = 0; r < 8; ++r) w64[r] = wrow(W, U, 8 * i64 + r, c64c);
        w64x = (i64 < 2) ? wrow(W, U, 128 + i64, c64c) : 0.0f;
    }
    const float b64i = b[64], b64f = b[129], b64g = b[194], b64o = b[259];
    const int ml = (wave >= 1 && wave <= 3) ? (wave - 1) : 0;

    float c_0 = 0, c_1 = 0, c_2 = 0, c64 = 0;      // cell states

    const float* xrow = x   + (size_t)e * SEQ * UNITS;
    float*       orow = out + (size_t)e * SEQ * UNITS;
    const int ipI = inpos16(j), ipH = inpos16(65 + j);

    // ---- init: zero LDS (pads + h-parts must be 0), then v0.in = x(0) ----
    for (int i = tid; i < 2 * 3 * LAYER; i += 1024) ((float*)&vbuf[0][0][0])[i] = 0.0f;
    __syncthreads();
    if (wr)  vbuf[0][0][ipI] = xrow[j];
    if (wave == 1 && lane == 0) vbuf[0][0][96] = xrow[64];   // inpos16(64)=96
    __syncthreads();

    // x prefetch: xq0 holds x(s+1) value at end of step s
    float xq0 = 0, ex0 = 0;
    if (wr) xq0 = xrow[UNITS + j];
    if (wave == 1 && lane == 0) ex0 = xrow[UNITS + 64];

    float* const vb0 = &vbuf[0][0][0];
    float* const vb1 = &vbuf[1][0][0];
    int s = 0;
    STEP(1, 0, 0, vb0, vb1); ++s;               // s=0: layer0 only
    STEP(1, 1, 0, vb1, vb0); ++s;               // s=1: layers 0,1
    for (; s < SEQ - 1; ) {                     // s=2..SEQ-1 (8190 steps, even)
        STEP(1, 1, 1, vb0, vb1); ++s;
        STEP(1, 1, 1, vb1, vb0); ++s;
    }
    STEP(0, 1, 1, vb0, vb1); ++s;               // s=SEQ: layers 1,2
    STEP(0, 0, 1, vb1, vb0);                    // s=SEQ+1: layer 2 drains
}

// Dense head, in place on d_out: out_row = row @ Wd + bd. One thread per row.
__global__ __launch_bounds__(256)
void dense_kernel(float* __restrict__ io,
                  const float* __restrict__ Wd,
                  const float* __restrict__ bd)
{
    __shared__ __attribute__((aligned(16))) float wS[65 * 68];
    __shared__ float bS[65];
    for (int i = threadIdx.x; i < 65 * 65; i += 256) {
        int r = i / 65, c = i - r * 65;
        wS[r * 68 + c] = Wd[i];
    }
    if (threadIdx.x < 65) bS[threadIdx.x] = bd[threadIdx.x];
    __syncthreads();

    const size_t row  = (size_t)blockIdx.x * 256 + threadIdx.x;
    const size_t base = row * 65;

    float r[65];
    #pragma unroll
    for (int k = 0; k < 65; ++k) r[k] = io[base + k];

    for (int ct = 0; ct < 16; ++ct) {
        const int c = ct * 4;
        float a0 = bS[c], a1 = bS[c + 1], a2 = bS[c + 2], a3 = bS[c + 3];
        #pragma unroll
        for (int k = 0; k < 65; ++k) {
            const float4 wv = *reinterpret_cast<const float4*>(&wS[k * 68 + c]);
            a0 += r[k] * wv.x;
            a1 += r[k] * wv.y;
            a2 += r[k] * wv.z;
            a3 += r[k] * wv.w;
        }
        io[base + c]     = a0;
        io[base + c + 1] = a1;
        io[base + c + 2] = a2;
        io[base + c + 3] = a3;
    }
    float a = bS[64];
    #pragma unroll
    for (int k = 0; k < 65; ++k) a += r[k] * wS[k * 68 + 64];
    io[base + 64] = a;
}

extern "C" void kernel_launch(void* const* d_in, const int* in_sizes, int n_in,
                              void* d_out, int out_size, void* d_ws, size_t ws_size,
                              hipStream_t stream)
{
    const float* x  = (const float*)d_in[0];
    const float* W  = (const float*)d_in[1];
    const float* U  = (const float*)d_in[2];
    const float* b  = (const float*)d_in[3];
    const float* Wd = (const float*)d_in[4];
    const float* bd = (const float*)d_in[5];
    float* out = (float*)d_out;

    hipLaunchKernelGGL(lstm3_kernel, dim3(BATCH), dim3(1024), 0, stream, x, W, U, b, out);
    hipLaunchKernelGGL(dense_kernel, dim3(1600), dim3(256), 0, stream, out, Wd, bd);
}